// Round 6
// baseline (28.916 us; speedup 1.0000x reference)
//
#include <hip/hip_runtime.h>
#include <math.h>

// ChamferLoss via matrix cores — full-rate v_mfma_f32_32x32x16_f16 (K=16).
// Embedding (K=16, only k=0..4 used, rest zero):
//   A-side a: (ax,ay,az, 1, -|a|^2/2, 0...)
//   B-side b: (bx,by,bz, -|b|^2/2, 1, 0...)
// => C[i][j] = a.b - (|a|^2+|b|^2)/2 = -dist^2(a,b)/2 ; min dist^2 = -2 max C.
// Lanes 32..63 hold k=8..15 => all-zero fragments (stored zeroed in LDS).
// Each wave owns TWO col-tiles so one A-frag ds_read_b128 feeds two MFMAs.

typedef _Float16 half8 __attribute__((ext_vector_type(8)));
typedef float floatx16 __attribute__((ext_vector_type(16)));

constexpr int B_ = 64;
constexpr int N_ = 2048;
constexpr int NT = N_ / 32;        // 64 tiles per side
constexpr int BLOCK = 512;         // 8 waves
constexpr int WPB = 8;
constexpr int BFRAGS = 2;          // col-tiles per wave
constexpr int IBLK = NT / (WPB * BFRAGS);   // 4 blocks along col-tile axis

__global__ __launch_bounds__(BLOCK, 4) void chamfer_mfma_kernel(
    const float* __restrict__ p, const float* __restrict__ q,
    float* __restrict__ out)
{
    __shared__ half8 Aarr[NT * 64];       // 64 KB: per-tile A fragments
    __shared__ float wsum[WPB];

    const int dir = blockIdx.z;            // 0: A=q,B=p ; 1: A=p,B=q
    const int b   = blockIdx.y;
    const float4* rowsA = (const float4*)((dir == 0 ? q : p) + (size_t)b * N_ * 4);
    const float4* colsB = (const float4*)((dir == 0 ? p : q) + (size_t)b * N_ * 4);

    // Build all A-role fragments for this batch in LDS.
    // A frag layout (32x32x16f16): lane l holds A[row=l%32][k=8*(l/32)+e].
    for (int j = threadIdx.x; j < N_; j += BLOCK) {
        float4 v = rowsA[j];
        _Float16 x = (_Float16)v.y, y = (_Float16)v.z, z = (_Float16)v.w;
        float xf = (float)x, yf = (float)y, zf = (float)z;
        float sq = fmaf(xf, xf, fmaf(yf, yf, zf * zf));
        half8 lo;
        lo[0] = x; lo[1] = y; lo[2] = z; lo[3] = (_Float16)1.0f;
        lo[4] = (_Float16)(-0.5f * sq);
        lo[5] = (_Float16)0.0f; lo[6] = (_Float16)0.0f; lo[7] = (_Float16)0.0f;
        half8 zero8;
#pragma unroll
        for (int e = 0; e < 8; ++e) zero8[e] = (_Float16)0.0f;
        const int tile = j >> 5, r = j & 31;
        Aarr[tile * 64 + r]      = lo;     // lanes 0..31: k=0..7
        Aarr[tile * 64 + 32 + r] = zero8;  // lanes 32..63: k=8..15 (zero)
    }

    // Two B-role fragments per wave (col-tiles 2W and 2W+1).
    // B frag layout: lane l holds B[k=8*(l/32)+e][col=l%32].
    const int lane = threadIdx.x & 63;
    const int wid  = threadIdx.x >> 6;
    const int W    = blockIdx.x * WPB + wid;
    half8 bf[BFRAGS];
#pragma unroll
    for (int t = 0; t < BFRAGS; ++t) {
        float4 v = colsB[(W * BFRAGS + t) * 32 + (lane & 31)];
        _Float16 x = (_Float16)v.y, y = (_Float16)v.z, z = (_Float16)v.w;
        float xf = (float)x, yf = (float)y, zf = (float)z;
        float sq = fmaf(xf, xf, fmaf(yf, yf, zf * zf));
#pragma unroll
        for (int e = 0; e < 8; ++e) bf[t][e] = (_Float16)0.0f;
        if (lane < 32) {
            bf[t][0] = x; bf[t][1] = y; bf[t][2] = z;
            bf[t][3] = (_Float16)(-0.5f * sq);
            bf[t][4] = (_Float16)1.0f;
        }
    }
    __syncthreads();

    floatx16 zero;
#pragma unroll
    for (int i = 0; i < 16; ++i) zero[i] = 0.0f;

    // Sweep all row-tiles; one A-frag ds_read_b128 feeds BFRAGS MFMAs.
    float cmx0 = -3.4e38f, cmx1 = -3.4e38f;
#pragma unroll 4
    for (int J = 0; J < NT; ++J) {
        half8 afrag = Aarr[J * 64 + lane];
        floatx16 C0 = __builtin_amdgcn_mfma_f32_32x32x16_f16(afrag, bf[0], zero, 0, 0, 0);
        floatx16 C1 = __builtin_amdgcn_mfma_f32_32x32x16_f16(afrag, bf[1], zero, 0, 0, 0);
        {
            float m0 = fmaxf(fmaxf(C0[0],  C0[1]),  C0[2]);
            float m1 = fmaxf(fmaxf(C0[3],  C0[4]),  C0[5]);
            float m2 = fmaxf(fmaxf(C0[6],  C0[7]),  C0[8]);
            float m3 = fmaxf(fmaxf(C0[9],  C0[10]), C0[11]);
            float m4 = fmaxf(fmaxf(C0[12], C0[13]), C0[14]);
            float m5 = fmaxf(fmaxf(m0, m1), C0[15]);
            float m6 = fmaxf(fmaxf(m2, m3), m4);
            cmx0 = fmaxf(cmx0, fmaxf(m5, m6));
        }
        {
            float m0 = fmaxf(fmaxf(C1[0],  C1[1]),  C1[2]);
            float m1 = fmaxf(fmaxf(C1[3],  C1[4]),  C1[5]);
            float m2 = fmaxf(fmaxf(C1[6],  C1[7]),  C1[8]);
            float m3 = fmaxf(fmaxf(C1[9],  C1[10]), C1[11]);
            float m4 = fmaxf(fmaxf(C1[12], C1[13]), C1[14]);
            float m5 = fmaxf(fmaxf(m0, m1), C1[15]);
            float m6 = fmaxf(fmaxf(m2, m3), m4);
            cmx1 = fmaxf(cmx1, fmaxf(m5, m6));
        }
    }

    // Combine the two lane-halves; each column then held by 2 lanes.
    cmx0 = fmaxf(cmx0, __shfl_xor(cmx0, 32, 64));
    cmx1 = fmaxf(cmx1, __shfl_xor(cmx1, 32, 64));

    float local = sqrtf(fmaxf(-2.0f * cmx0, 0.0f) + 1e-16f)
                + sqrtf(fmaxf(-2.0f * cmx1, 0.0f) + 1e-16f);

#pragma unroll
    for (int off = 32; off > 0; off >>= 1)
        local += __shfl_xor(local, off, 64);

    if (lane == 0) wsum[wid] = local;
    __syncthreads();
    if (threadIdx.x == 0) {
        float s = 0.0f;
#pragma unroll
        for (int w = 0; w < WPB; ++w) s += wsum[w];
        atomicAdd(out, 0.25f * s);   // 0.5 chamfer factor * 0.5 lane-dup
    }
}

extern "C" void kernel_launch(void* const* d_in, const int* in_sizes, int n_in,
                              void* d_out, int out_size, void* d_ws, size_t ws_size,
                              hipStream_t stream) {
    const float* p = (const float*)d_in[0];
    const float* q = (const float*)d_in[1];
    float* out = (float*)d_out;

    hipMemsetAsync(out, 0, sizeof(float), stream);

    dim3 grid(IBLK, B_, 2);                 // 4 x 64 x 2 = 512 blocks
    chamfer_mfma_kernel<<<grid, BLOCK, 0, stream>>>(p, q, out);
}